// Round 13
// baseline (27.934 us; speedup 1.0000x reference)
//
#include <hip/hip_runtime.h>

// Sample_PDF: R=65536 rays, N=64, F=128. TWO rays per wave, chains
// register-interleaved. Search = 3 register-compare levels (readlane probes)
// + ONE parallel probe round (7 independent bpermutes of cdf[lo+1..lo+7],
// position = sum of compares) + 1 gather round. Dependent LDS round-trips
// on the critical path: 2 (was 4). LDS-free otherwise; per-bin linear
// coeffs; ballot path for s[128]; non-temporal dwordx4 stores.

#define WAVES_PER_BLOCK 4
#define DPP_WAVE_SHL1 0x130
#define DPP_WAVE_SHR1 0x138

typedef float fvec4 __attribute__((ext_vector_type(4)));

template <int CTRL, int ROW_MASK>
__device__ __forceinline__ float dpp_add(float x) {
    int sh = __builtin_amdgcn_update_dpp(0, __float_as_int(x), CTRL, ROW_MASK, 0xf, false);
    return x + __int_as_float(sh);
}

// lane i gets src from lane i-1 (SHR) / i+1 (SHL); boundary lane gets `old`.
template <int CTRL>
__device__ __forceinline__ float dpp_old_f(float old, float src) {
    return __int_as_float(__builtin_amdgcn_update_dpp(
        __float_as_int(old), __float_as_int(src), CTRL, 0xf, 0xf, false));
}

__device__ __forceinline__ float readlane_f(float v, int lane) {
    return __int_as_float(__builtin_amdgcn_readlane(__float_as_int(v), lane));
}

__device__ __forceinline__ float bperm(int byteaddr, float v) {
    return __int_as_float(__builtin_amdgcn_ds_bpermute(byteaddr, __float_as_int(v)));
}

// cdf[m] (m=1..64) lives at lane m-1 of cdfv. Returns 4*lo with
// cdf[lo] <= uu < cdf[lo+1], lo in [0,63].
// 3 register levels narrow to an 8-wide window; then ONE round of 7
// independent bpermute probes resolves the final 3 bits via compare-sum.
__device__ __forceinline__ int search_par(float uu, float cdfv,
                                          float c8, float c16, float c24, float c32,
                                          float c40, float c48, float c56) {
    bool g1 = (c32 <= uu);
    int loB = g1 ? 128 : 0;
    float cA = g1 ? c48 : c16;
    bool g2 = (cA <= uu);
    loB += g2 ? 64 : 0;
    float pL = g1 ? c40 : c8;
    float pH = g1 ? c56 : c24;
    float cB = g2 ? pH : pL;
    loB += (cB <= uu) ? 32 : 0;
    // 7 independent probes: cdf[lo+k] @ lane lo+k-1, k=1..7 (one lgkm round)
    float p1 = bperm(loB +  0, cdfv);
    float p2 = bperm(loB +  4, cdfv);
    float p3 = bperm(loB +  8, cdfv);
    float p4 = bperm(loB + 12, cdfv);
    float p5 = bperm(loB + 16, cdfv);
    float p6 = bperm(loB + 20, cdfv);
    float p7 = bperm(loB + 24, cdfv);
    int cnt = (int)(p1 <= uu) + (int)(p2 <= uu) + (int)(p3 <= uu)
            + (int)(p4 <= uu) + (int)(p5 <= uu) + (int)(p6 <= uu)
            + (int)(p7 <= uu);                   // window is sorted -> count = offset
    return loB + (cnt << 2);
}

__device__ __forceinline__ fvec4 ray_body(float w, float2 ti, float u0, float u1, float u2,
                                          int lane) {
    // maxblur
    float wm1 = dpp_old_f<DPP_WAVE_SHR1>(w, w);
    float wp1 = dpp_old_f<DPP_WAVE_SHL1>(w, w);
    float w2 = (fmaxf(wm1, w) + fmaxf(w, wp1)) * 0.5f + 0.01f;

    // inclusive scan (canonical gfx9 DPP, 6 ops)
    float scan = w2;
    scan = dpp_add<0x111, 0xf>(scan);
    scan = dpp_add<0x112, 0xf>(scan);
    scan = dpp_add<0x114, 0xf>(scan);
    scan = dpp_add<0x118, 0xf>(scan);
    scan = dpp_add<0x142, 0xa>(scan);
    scan = dpp_add<0x143, 0xc>(scan);

    // padding term provably 0 (wsum >= 0.64 >> 1e-5); fmin(1,.) <=1e-7 -> dropped
    float wsum = readlane_f(scan, 63);
    float cdfv = scan * __builtin_amdgcn_rcpf(wsum);
    if (lane == 63) cdfv = 1.0f;

    // per-bin linear coeffs: sample(u in bin l) = A[l] + B[l]*u
    float clo = dpp_old_f<DPP_WAVE_SHR1>(0.0f, cdfv);
    float nx  = dpp_old_f<DPP_WAVE_SHL1>(ti.y, ti.x);
    float dt  = nx - ti.x;
    float Bv  = dt * __builtin_amdgcn_rcpf(cdfv - clo);
    float Av  = ti.x - clo * Bv;

    // s[128]: wave-uniform u2 -> ballot + popcount, scalar gathers
    unsigned long long mask = __ballot(cdfv <= u2);
    int p = __popcll(mask);
    float s2 = readlane_f(Av, p) + readlane_f(Bv, p) * u2;

    // probes for the top 3 search levels
    float c8  = readlane_f(cdfv, 7),  c16 = readlane_f(cdfv, 15);
    float c24 = readlane_f(cdfv, 23), c32 = readlane_f(cdfv, 31);
    float c40 = readlane_f(cdfv, 39), c48 = readlane_f(cdfv, 47);
    float c56 = readlane_f(cdfv, 55);

    int lA = search_par(u0, cdfv, c8, c16, c24, c32, c40, c48, c56);
    int lB = search_par(u1, cdfv, c8, c16, c24, c32, c40, c48, c56);
    float s_a = bperm(lA, Av) + bperm(lA, Bv) * u0;     // s[2l]
    float s_b = bperm(lB, Av) + bperm(lB, Bv) * u1;     // s[2l+1]

    // s[2l+2] = next lane's s_a; lane63 -> s2
    float s_an = dpp_old_f<DPP_WAVE_SHL1>(s2, s_a);

    fvec4 o4 = { s_a, s_b, s_b, s_an };
    return o4;
}

__global__ __launch_bounds__(64 * WAVES_PER_BLOCK)
void sample_pdf_kernel(const float* __restrict__ weights,   // [R,64]
                       const float* __restrict__ t_inters,  // [R,64,2]
                       const float* __restrict__ u,         // [R,129]
                       float* __restrict__ out,             // [R,128,2]
                       int R) {
    const int lane = threadIdx.x & 63;
    const int wave = threadIdx.x >> 6;
    const int rayA = (blockIdx.x * WAVES_PER_BLOCK + wave) * 2;
    const int rayB = rayA + 1;

    // ---- both rays' loads issued together (one vmcnt group)
    float  wA  = weights[(long)rayA * 64 + lane];
    float  wB  = weights[(long)rayB * 64 + lane];
    float2 tiA = ((const float2*)t_inters)[(long)rayA * 64 + lane];
    float2 tiB = ((const float2*)t_inters)[(long)rayB * 64 + lane];
    const float* ubA = u + (long)rayA * 129;
    const float* ubB = u + (long)rayB * 129;
    float u0A = ubA[2 * lane], u1A = ubA[2 * lane + 1], u2A = ubA[128];
    float u0B = ubB[2 * lane], u1B = ubB[2 * lane + 1], u2B = ubB[128];

    // ---- two independent chains; scheduler interleaves them
    fvec4 oA = ray_body(wA, tiA, u0A, u1A, u2A, lane);
    fvec4 oB = ray_body(wB, tiB, u0B, u1B, u2B, lane);

    __builtin_nontemporal_store(oA, &((fvec4*)out)[(long)rayA * 64 + lane]);
    __builtin_nontemporal_store(oB, &((fvec4*)out)[(long)rayB * 64 + lane]);
}

extern "C" void kernel_launch(void* const* d_in, const int* in_sizes, int n_in,
                              void* d_out, int out_size, void* d_ws, size_t ws_size,
                              hipStream_t stream) {
    const float* weights  = (const float*)d_in[0];
    const float* t_inters = (const float*)d_in[1];
    const float* u        = (const float*)d_in[2];
    float* out            = (float*)d_out;

    const int R = in_sizes[0] / 64;                       // 65536
    const int rays_per_block = WAVES_PER_BLOCK * 2;       // 8
    const int grid = (R + rays_per_block - 1) / rays_per_block;   // 8192
    sample_pdf_kernel<<<grid, 64 * WAVES_PER_BLOCK, 0, stream>>>(weights, t_inters, u, out, R);
}

// Round 14
// 27.172 us; speedup vs baseline: 1.0280x; 1.0280x over previous
//
#include <hip/hip_runtime.h>

// Sample_PDF: R=65536 rays, N=64, F=128. TWO rays per wave (best measured
// config: 27.16us R9, 27.33us R12 repro), chains register-interleaved so
// each dependent DPP/readlane/bpermute hop of ray A is filled by ray B.
// LDS-free; per-bin linear coeffs; ballot path for s[128]; nt dwordx4 store.

#define WAVES_PER_BLOCK 4
#define DPP_WAVE_SHL1 0x130
#define DPP_WAVE_SHR1 0x138

typedef float fvec4 __attribute__((ext_vector_type(4)));

template <int CTRL, int ROW_MASK>
__device__ __forceinline__ float dpp_add(float x) {
    int sh = __builtin_amdgcn_update_dpp(0, __float_as_int(x), CTRL, ROW_MASK, 0xf, false);
    return x + __int_as_float(sh);
}

// lane i gets src from lane i-1 (SHR) / i+1 (SHL); boundary lane gets `old`.
template <int CTRL>
__device__ __forceinline__ float dpp_old_f(float old, float src) {
    return __int_as_float(__builtin_amdgcn_update_dpp(
        __float_as_int(old), __float_as_int(src), CTRL, 0xf, 0xf, false));
}

__device__ __forceinline__ float readlane_f(float v, int lane) {
    return __int_as_float(__builtin_amdgcn_readlane(__float_as_int(v), lane));
}

__device__ __forceinline__ float bperm(int byteaddr, float v) {
    return __int_as_float(__builtin_amdgcn_ds_bpermute(byteaddr, __float_as_int(v)));
}

// cdf[m] (m=1..64) lives at lane m-1 of cdfv. Returns 4*lo with
// cdf[lo] <= uu < cdf[lo+1], lo in [0,63].
__device__ __forceinline__ int search6(float uu, float cdfv,
                                       float c8, float c16, float c24, float c32,
                                       float c40, float c48, float c56) {
    bool g1 = (c32 <= uu);
    int loB = g1 ? 128 : 0;
    float cA = g1 ? c48 : c16;
    bool g2 = (cA <= uu);
    loB += g2 ? 64 : 0;
    float pL = g1 ? c40 : c8;
    float pH = g1 ? c56 : c24;
    float cB = g2 ? pH : pL;
    loB += (cB <= uu) ? 32 : 0;
    float c = bperm(loB + 12, cdfv);   // cdf[lo+4] @ lane lo+3
    loB += (c <= uu) ? 16 : 0;
    c = bperm(loB + 4, cdfv);          // cdf[lo+2] @ lane lo+1
    loB += (c <= uu) ? 8 : 0;
    c = bperm(loB, cdfv);              // cdf[lo+1] @ lane lo
    loB += (c <= uu) ? 4 : 0;
    return loB;
}

__device__ __forceinline__ fvec4 ray_body(float w, float2 ti, float u0, float u1, float u2,
                                          int lane) {
    // maxblur
    float wm1 = dpp_old_f<DPP_WAVE_SHR1>(w, w);
    float wp1 = dpp_old_f<DPP_WAVE_SHL1>(w, w);
    float w2 = (fmaxf(wm1, w) + fmaxf(w, wp1)) * 0.5f + 0.01f;

    // inclusive scan (canonical gfx9 DPP, 6 ops)
    float scan = w2;
    scan = dpp_add<0x111, 0xf>(scan);
    scan = dpp_add<0x112, 0xf>(scan);
    scan = dpp_add<0x114, 0xf>(scan);
    scan = dpp_add<0x118, 0xf>(scan);
    scan = dpp_add<0x142, 0xa>(scan);
    scan = dpp_add<0x143, 0xc>(scan);

    // padding term provably 0 (wsum >= 0.64 >> 1e-5); fmin(1,.) <=1e-7 -> dropped
    float wsum = readlane_f(scan, 63);
    float cdfv = scan * __builtin_amdgcn_rcpf(wsum);
    if (lane == 63) cdfv = 1.0f;

    // per-bin linear coeffs: sample(u in bin l) = A[l] + B[l]*u
    float clo = dpp_old_f<DPP_WAVE_SHR1>(0.0f, cdfv);
    float nx  = dpp_old_f<DPP_WAVE_SHL1>(ti.y, ti.x);
    float dt  = nx - ti.x;
    float Bv  = dt * __builtin_amdgcn_rcpf(cdfv - clo);
    float Av  = ti.x - clo * Bv;

    // s[128]: wave-uniform u2 -> ballot + popcount, scalar gathers
    unsigned long long mask = __ballot(cdfv <= u2);
    int p = __popcll(mask);
    float s2 = readlane_f(Av, p) + readlane_f(Bv, p) * u2;

    // probes for the top 3 search levels
    float c8  = readlane_f(cdfv, 7),  c16 = readlane_f(cdfv, 15);
    float c24 = readlane_f(cdfv, 23), c32 = readlane_f(cdfv, 31);
    float c40 = readlane_f(cdfv, 39), c48 = readlane_f(cdfv, 47);
    float c56 = readlane_f(cdfv, 55);

    int lA = search6(u0, cdfv, c8, c16, c24, c32, c40, c48, c56);
    int lB = search6(u1, cdfv, c8, c16, c24, c32, c40, c48, c56);
    float s_a = bperm(lA, Av) + bperm(lA, Bv) * u0;     // s[2l]
    float s_b = bperm(lB, Av) + bperm(lB, Bv) * u1;     // s[2l+1]

    // s[2l+2] = next lane's s_a; lane63 -> s2
    float s_an = dpp_old_f<DPP_WAVE_SHL1>(s2, s_a);

    fvec4 o4 = { s_a, s_b, s_b, s_an };
    return o4;
}

__global__ __launch_bounds__(64 * WAVES_PER_BLOCK)
void sample_pdf_kernel(const float* __restrict__ weights,   // [R,64]
                       const float* __restrict__ t_inters,  // [R,64,2]
                       const float* __restrict__ u,         // [R,129]
                       float* __restrict__ out,             // [R,128,2]
                       int R) {
    const int lane = threadIdx.x & 63;
    const int wave = threadIdx.x >> 6;
    const int rayA = (blockIdx.x * WAVES_PER_BLOCK + wave) * 2;
    const int rayB = rayA + 1;

    // ---- both rays' loads issued together (one vmcnt group)
    float  wA  = weights[(long)rayA * 64 + lane];
    float  wB  = weights[(long)rayB * 64 + lane];
    float2 tiA = ((const float2*)t_inters)[(long)rayA * 64 + lane];
    float2 tiB = ((const float2*)t_inters)[(long)rayB * 64 + lane];
    const float* ubA = u + (long)rayA * 129;
    const float* ubB = u + (long)rayB * 129;
    float u0A = ubA[2 * lane], u1A = ubA[2 * lane + 1], u2A = ubA[128];
    float u0B = ubB[2 * lane], u1B = ubB[2 * lane + 1], u2B = ubB[128];

    // ---- two independent chains; scheduler interleaves them
    fvec4 oA = ray_body(wA, tiA, u0A, u1A, u2A, lane);
    fvec4 oB = ray_body(wB, tiB, u0B, u1B, u2B, lane);

    __builtin_nontemporal_store(oA, &((fvec4*)out)[(long)rayA * 64 + lane]);
    __builtin_nontemporal_store(oB, &((fvec4*)out)[(long)rayB * 64 + lane]);
}

extern "C" void kernel_launch(void* const* d_in, const int* in_sizes, int n_in,
                              void* d_out, int out_size, void* d_ws, size_t ws_size,
                              hipStream_t stream) {
    const float* weights  = (const float*)d_in[0];
    const float* t_inters = (const float*)d_in[1];
    const float* u        = (const float*)d_in[2];
    float* out            = (float*)d_out;

    const int R = in_sizes[0] / 64;                       // 65536
    const int rays_per_block = WAVES_PER_BLOCK * 2;       // 8
    const int grid = (R + rays_per_block - 1) / rays_per_block;   // 8192
    sample_pdf_kernel<<<grid, 64 * WAVES_PER_BLOCK, 0, stream>>>(weights, t_inters, u, out, R);
}